// Round 16
// baseline (155.390 us; speedup 1.0000x reference)
//
#include <hip/hip_runtime.h>

// Problem constants
#define NB 8
#define NS 1024
#define NE 768
#define NH 12
#define ND 64

typedef __attribute__((ext_vector_type(8))) short bf16x8;
typedef __attribute__((ext_vector_type(4))) float f32x4;
typedef __attribute__((ext_vector_type(16))) float f32x16;
typedef const __attribute__((address_space(1))) void gv_t;
typedef __attribute__((address_space(3))) void sv_t;

static __device__ __forceinline__ ushort f2bf(float f) {
  union { float f; unsigned u; } c; c.f = f;
  unsigned u = c.u + 0x7fffu + ((c.u >> 16) & 1u);
  return (ushort)(u >> 16);
}
static __device__ __forceinline__ float bf2f(ushort h) {
  union { unsigned u; float f; } c; c.u = ((unsigned)h) << 16;
  return c.f;
}
static __device__ __forceinline__ uint pk_bf16(float lo, float hi) {
  uint r;
  asm("v_cvt_pk_bf16_f32 %0, %1, %2" : "=v"(r) : "v"(lo), "v"(hi));
  return r;
}
// exchange lane halves (distinct, well-aged registers only)
#define PL32SWAP(a, b) asm("v_permlane32_swap_b32 %0, %1" : "+v"(a), "+v"(b))
#define GLDS16(src, dst) __builtin_amdgcn_global_load_lds((gv_t*)(src), (sv_t*)(dst), 16, 0, 0)

// ---------------- f32 -> bf16 conversion (x + all weights, one launch) ----------------
__global__ void cvt_all(const float* __restrict__ x,
                        const float* __restrict__ w0, const float* __restrict__ w1,
                        const float* __restrict__ w2, const float* __restrict__ w3,
                        const float* __restrict__ w4,
                        ushort* __restrict__ xd,
                        ushort* __restrict__ o0, ushort* __restrict__ o1,
                        ushort* __restrict__ o2, ushort* __restrict__ o3,
                        ushort* __restrict__ o4) {
  int blk = blockIdx.x;
  const float* src; ushort* dst; int idx;
  if (blk < 6144) {
    src = x; dst = xd; idx = blk;
  } else if (blk < 8448) {
    int b = blk - 6144;
    int ws = b / 576;
    src = (ws == 0) ? w0 : (ws == 1) ? w1 : (ws == 2) ? w2 : w3;
    dst = (ws == 0) ? o0 : (ws == 1) ? o1 : (ws == 2) ? o2 : o3;
    idx = b % 576;
  } else {
    src = w4; dst = o4; idx = blk - 8448;
  }
  int i = (idx * 256 + threadIdx.x) * 4;
  float4 f = *(const float4*)(src + i);
  ushort4 o;
  o.x = f2bf(f.x); o.y = f2bf(f.y); o.z = f2bf(f.z); o.w = f2bf(f.w);
  *(ushort4*)(dst + i) = o;
}

// ---------------- GEMM core: C[128x128] tile of A[M,768] @ B[N,768]^T ----------------
// 2-phase double-buffered with COUNTED vmcnt (T4): stage kt+1 issued at top of
// step kt and stays in flight across the whole compute phase; each wave waits
// only vmcnt(4) (its own stage(kt) loads) before barrier #1. lgkmcnt(0) +
// barrier #2 before MFMA licenses next step's overwrite of the read buffer.
// S0 layout (ushorts): As0@0, Bs0@4096, As1@8192, Bs1@12288.
__device__ __forceinline__ void gemm_core(const ushort* __restrict__ A,
                                          const ushort* __restrict__ Bw,
                                          ushort* S0,
                                          int bm0, int bn0, f32x4 (&acc)[4][4]) {
  const int tid = threadIdx.x;
  const int w = tid >> 6, lane = tid & 63;
  const int l15 = lane & 15, l4 = lane >> 4;
  const int wm = w >> 1, wn = w & 1;
  const int row = tid >> 2, seg = tid & 3;

#define STAGE_KT(KT, B)                                                        \
  { ushort* As_ = S0 + (B) * 8192; ushort* Bs_ = As_ + 4096;                   \
    _Pragma("unroll")                                                          \
    for (int p = 0; p < 2; ++p) {                                              \
      const ushort* ga = A + (size_t)(bm0 + p * 64 + row) * 768 + (KT) * 32 + seg * 8; \
      GLDS16(ga, As_ + (p * 256 + w * 64) * 8);                                \
      const ushort* gb = Bw + (size_t)(bn0 + p * 64 + row) * 768 + (KT) * 32 + seg * 8; \
      GLDS16(gb, Bs_ + (p * 256 + w * 64) * 8);                                \
    } }

  STAGE_KT(0, 0)   // 4 glds in flight

  #pragma unroll 2
  for (int kt = 0; kt < 24; ++kt) {
    if (kt < 23) { STAGE_KT(kt + 1, (kt + 1) & 1) }   // +4 -> 8 in flight

    // wait only for stage(kt); stage(kt+1) stays in flight across compute
    if (kt < 23) { asm volatile("s_waitcnt vmcnt(4)" ::: "memory"); }
    else         { asm volatile("s_waitcnt vmcnt(0)" ::: "memory"); }
    __builtin_amdgcn_sched_barrier(0);
    __builtin_amdgcn_s_barrier();      // #1: all waves' stage(kt) landed
    __builtin_amdgcn_sched_barrier(0);

    ushort* As = S0 + (kt & 1) * 8192;
    ushort* Bs = As + 4096;
    bf16x8 af[4], bf[4];
    #pragma unroll
    for (int mi = 0; mi < 4; ++mi)
      af[mi] = *(const bf16x8*)(As + (wm * 64 + mi * 16 + l15) * 32 + l4 * 8);
    #pragma unroll
    for (int ni = 0; ni < 4; ++ni)
      bf[ni] = *(const bf16x8*)(Bs + (wn * 64 + ni * 16 + l15) * 32 + l4 * 8);

    asm volatile("s_waitcnt lgkmcnt(0)" ::: "memory");
    __builtin_amdgcn_sched_barrier(0);
    __builtin_amdgcn_s_barrier();      // #2: all waves' ds_reads done ->
    __builtin_amdgcn_sched_barrier(0); //     next STAGE may overwrite this buf

    #pragma unroll
    for (int mi = 0; mi < 4; ++mi)
      #pragma unroll
      for (int ni = 0; ni < 4; ++ni)
        acc[mi][ni] = __builtin_amdgcn_mfma_f32_16x16x32_bf16(af[mi], bf[ni], acc[mi][ni], 0, 0, 0);
  }
#undef STAGE_KT
}

// QKV: blockIdx.y in [0,18): wsel = y/6 picks W/dst, bn = y%6
// q (PRE-SCALED by 1/sqrt(64)*log2e) written [bh][s][d].
// k written FRAG-LINEAR k4[bh][s>>5][d>>4][(d>>3)&1][s&31][d&7]
// v written FRAG-LINEAR v4[bh][s>>5][(d>>5)*2+((s>>4)&1)][(s>>3)&1][d&31][s&7]
__global__ __launch_bounds__(256)
void gemm_qkv(const ushort* __restrict__ A,
              const ushort* __restrict__ B0, const ushort* __restrict__ B1, const ushort* __restrict__ B2,
              ushort* __restrict__ C0, ushort* __restrict__ C1, ushort* __restrict__ C2) {
  __shared__ __align__(16) char gsm[34816];   // 32KB dbuf; VtS [128][136] aliases
  ushort* S0 = (ushort*)gsm;
  ushort* VtS = (ushort*)gsm;

  const int wsel = blockIdx.y / 6;
  const int bn0 = (blockIdx.y % 6) * 128;
  const int bx = blockIdx.x;
  const int bm0 = (((bx & 7) << 3) + (bx >> 3)) * 128;   // XCD-chunked swizzle
  const ushort* Bw = (wsel == 0) ? B0 : (wsel == 1) ? B1 : B2;
  ushort* Co = (wsel == 0) ? C0 : (wsel == 1) ? C1 : C2;

  f32x4 acc[4][4];
  #pragma unroll
  for (int i = 0; i < 4; ++i)
    #pragma unroll
    for (int j = 0; j < 4; ++j)
      acc[i][j] = (f32x4){0.f, 0.f, 0.f, 0.f};

  gemm_core(A, Bw, S0, bm0, bn0, acc);

  const int tid = threadIdx.x;
  const int lane = tid & 63;
  const int w = tid >> 6;
  const int l15 = lane & 15, l4 = lane >> 4;
  const int wm = w >> 1, wn = w & 1;

  if (wsel == 2) {
    // transpose through LDS, then bf16x8 stores in v4 frag-linear layout
    __syncthreads();
    #pragma unroll
    for (int mi = 0; mi < 4; ++mi) {
      #pragma unroll
      for (int ni = 0; ni < 4; ++ni) {
        const int nl = wn * 64 + ni * 16 + l15;
        const int ml = wm * 64 + mi * 16 + l4 * 4;
        ushort4 pk;
        pk.x = f2bf(acc[mi][ni][0]); pk.y = f2bf(acc[mi][ni][1]);
        pk.z = f2bf(acc[mi][ni][2]); pk.w = f2bf(acc[mi][ni][3]);
        *(ushort4*)&VtS[nl * 136 + ml] = pk;
      }
    }
    __syncthreads();
    #pragma unroll
    for (int p = 0; p < 8; ++p) {
      const int n = p * 16 + (tid >> 4);
      const int m = (tid & 15) * 8;
      bf16x8 vv = *(const bf16x8*)&VtS[n * 136 + m];
      const int ng = bn0 + n, h = ng >> 6, d = ng & 63;
      const int mg = bm0 + m, b = mg >> 10, sl = mg & 1023;
      size_t off = (size_t)(b * NH + h) * 65536 + (size_t)(sl >> 5) * 2048
                 + (size_t)((d >> 5) * 2 + ((sl >> 4) & 1)) * 512
                 + ((sl >> 3) & 1) * 256 + (d & 31) * 8;
      *(bf16x8*)&Co[off] = vv;
    }
  } else if (wsel == 1) {
    // k4 frag-linear scatter
    #pragma unroll
    for (int mi = 0; mi < 4; ++mi) {
      #pragma unroll
      for (int ni = 0; ni < 4; ++ni) {
        #pragma unroll
        for (int e = 0; e < 4; ++e) {
          int m = bm0 + wm * 64 + mi * 16 + l4 * 4 + e;
          int n = bn0 + wn * 64 + ni * 16 + l15;
          int b = m >> 10, s = m & 1023, h = n >> 6, d = n & 63;
          size_t off = (size_t)(b * NH + h) * 65536 + (size_t)(s >> 5) * 2048
                     + (size_t)(d >> 4) * 512 + ((d >> 3) & 1) * 256
                     + (s & 31) * 8 + (d & 7);
          Co[off] = f2bf(acc[mi][ni][e]);
        }
      }
    }
  } else {
    const float scl = 0.18033688f;  // q: 1/8 * log2(e)
    #pragma unroll
    for (int mi = 0; mi < 4; ++mi) {
      #pragma unroll
      for (int ni = 0; ni < 4; ++ni) {
        #pragma unroll
        for (int e = 0; e < 4; ++e) {
          int m = bm0 + wm * 64 + mi * 16 + l4 * 4 + e;
          int n = bn0 + wn * 64 + ni * 16 + l15;
          int b = m >> 10, s = m & 1023, h = n >> 6, d = n & 63;
          Co[(size_t)(b * NH + h) * 65536 + (s << 6) + d] = f2bf(acc[mi][ni][e] * scl);
        }
      }
    }
  }
}

// Output projection: y[8192,768] @ Wp^T -> f32 out
__global__ __launch_bounds__(256)
void gemm_proj(const ushort* __restrict__ A, const ushort* __restrict__ Bw,
               float* __restrict__ Cout) {
  __shared__ __align__(16) ushort S0[16384];   // 32KB double-buffer
  const int bx = blockIdx.x;
  const int bm0 = (((bx & 7) << 3) + (bx >> 3)) * 128;   // XCD-chunked swizzle
  const int bn0 = blockIdx.y * 128;

  f32x4 acc[4][4];
  #pragma unroll
  for (int i = 0; i < 4; ++i)
    #pragma unroll
    for (int j = 0; j < 4; ++j)
      acc[i][j] = (f32x4){0.f, 0.f, 0.f, 0.f};

  gemm_core(A, Bw, S0, bm0, bn0, acc);

  const int lane = threadIdx.x & 63;
  const int w = threadIdx.x >> 6;
  const int l15 = lane & 15, l4 = lane >> 4;
  const int wm = w >> 1, wn = w & 1;
  #pragma unroll
  for (int mi = 0; mi < 4; ++mi) {
    #pragma unroll
    for (int ni = 0; ni < 4; ++ni) {
      #pragma unroll
      for (int e = 0; e < 4; ++e) {
        int m = bm0 + wm * 64 + mi * 16 + l4 * 4 + e;
        int n = bn0 + wn * 64 + ni * 16 + l15;
        Cout[(size_t)m * NE + n] = acc[mi][ni][e];
      }
    }
  }
}

// finish chunk: online softmax + P-pack + PV (uses/updates m_run,l_run,o0,o1)
// cross-half shfl only on the rare rescale path (trigger uses 64-lane __any).
#define FINISH_CHUNK(S, VF00, VF01, VF10, VF11)                               \
  {                                                                           \
    float m01 = fmaxf(S[0], S[1]),  m23 = fmaxf(S[2], S[3]);                  \
    float m45 = fmaxf(S[4], S[5]),  m67 = fmaxf(S[6], S[7]);                  \
    float m89 = fmaxf(S[8], S[9]),  mab = fmaxf(S[10], S[11]);                \
    float mcd = fmaxf(S[12], S[13]), mef = fmaxf(S[14], S[15]);               \
    float cmax = fmaxf(fmaxf(fmaxf(m01, m23), fmaxf(m45, m67)),               \
                       fmaxf(fmaxf(m89, mab), fmaxf(mcd, mef)));              \
    if (__any(cmax > m_run + 8.f)) {      /* rare; wave-uniform */            \
      cmax = fmaxf(cmax, __shfl_xor(cmax, 32));                               \
      const float m_new = fmaxf(m_run, cmax);                                 \
      const float sc = __builtin_amdgcn_exp2f(m_run - m_new);                 \
      l_run *= sc;                                                            \
      m_run = m_new;                                                          \
      _Pragma("unroll")                                                       \
      for (int i = 0; i < 16; ++i) { o0[i] *= sc; o1[i] *= sc; }              \
    }                                                                         \
    _Pragma("unroll")                                                         \
    for (int i = 0; i < 16; ++i)                                              \
      S[i] = __builtin_amdgcn_exp2f(S[i] - m_run);                            \
    {                                                                         \
      float t0 = S[0] + S[1],   t1 = S[2] + S[3];                             \
      float t2 = S[4] + S[5],   t3 = S[6] + S[7];                             \
      float t4 = S[8] + S[9],   t5 = S[10] + S[11];                           \
      float t6 = S[12] + S[13], t7 = S[14] + S[15];                           \
      t0 += t1; t2 += t3; t4 += t5; t6 += t7;                                 \
      l_run += (t0 + t2) + (t4 + t6);                                         \
    }                                                                         \
    uint a0 = pk_bf16(S[0],  S[1]);                                           \
    uint a1 = pk_bf16(S[2],  S[3]);                                           \
    uint a2 = pk_bf16(S[4],  S[5]);                                           \
    uint a3 = pk_bf16(S[6],  S[7]);                                           \
    uint a4 = pk_bf16(S[8],  S[9]);                                           \
    uint a5 = pk_bf16(S[10], S[11]);                                          \
    uint a6 = pk_bf16(S[12], S[13]);                                          \
    uint a7 = pk_bf16(S[14], S[15]);                                          \
    PL32SWAP(a0, a2);                                                         \
    PL32SWAP(a1, a3);                                                         \
    PL32SWAP(a4, a6);                                                         \
    PL32SWAP(a5, a7);                                                         \
    union FU { bf16x8 v; uint u[4]; } f0, f1;                                 \
    f0.u[0] = a0; f0.u[1] = a1; f0.u[2] = a2; f0.u[3] = a3;                   \
    f1.u[0] = a4; f1.u[1] = a5; f1.u[2] = a6; f1.u[3] = a7;                   \
    __builtin_amdgcn_s_setprio(1);                                            \
    o0 = __builtin_amdgcn_mfma_f32_32x32x16_bf16(VF00, f0.v, o0, 0, 0, 0);    \
    o0 = __builtin_amdgcn_mfma_f32_32x32x16_bf16(VF01, f1.v, o0, 0, 0, 0);    \
    o1 = __builtin_amdgcn_mfma_f32_32x32x16_bf16(VF10, f0.v, o1, 0, 0, 0);    \
    o1 = __builtin_amdgcn_mfma_f32_32x32x16_bf16(VF11, f1.v, o1, 0, 0, 0);    \
    __builtin_amdgcn_s_setprio(0);                                            \
  }

// bias C-init for a chunk (reads only Rl)
static __device__ __forceinline__ f32x16 bias_init(int dlt, const ushort* RlRow,
                                                   float c_lo, float c_hi,
                                                   int half4, int il) {
  f32x16 s;
  if (dlt <= -160 || dlt >= 160) {
    const float cv = (dlt < 0) ? c_lo : c_hi;
    #pragma unroll
    for (int i = 0; i < 16; ++i) s[i] = cv;
  } else {
    #pragma unroll
    for (int i = 0; i < 16; ++i) {
      const int rr = (i & 3) + 8 * (i >> 2) + half4;
      int rel = dlt + rr - il;
      rel = rel < -128 ? -128 : (rel > 127 ? 127 : rel);
      s[i] = bf2f(RlRow[rel & 255]);
    }
  }
  return s;
}

// load a chunk's K / V fragments (coalesced b128, frag-linear global layout)
#define LOADK(P, C)                                                           \
  k##P##0 = *(const bf16x8*)(kc + (C) * 2048);                                \
  k##P##1 = *(const bf16x8*)(kc + (C) * 2048 + 512);                          \
  k##P##2 = *(const bf16x8*)(kc + (C) * 2048 + 1024);                         \
  k##P##3 = *(const bf16x8*)(kc + (C) * 2048 + 1536);
#define LOADV(P, C)                                                           \
  v##P##0 = *(const bf16x8*)(vc + (C) * 2048);                                \
  v##P##1 = *(const bf16x8*)(vc + (C) * 2048 + 512);                          \
  v##P##2 = *(const bf16x8*)(vc + (C) * 2048 + 1024);                         \
  v##P##3 = *(const bf16x8*)(vc + (C) * 2048 + 1536);

// QK of chunk C into SREG (uses K set P), then prefetch K for C+2 into set P.
#define QK_CHUNK(C, P, SREG)                                                  \
  {                                                                           \
    SREG = bias_init(w * 256 + (C) * 32 - q0, RlRow, c_lo, c_hi, half4, il);  \
    __builtin_amdgcn_s_setprio(1);                                            \
    SREG = __builtin_amdgcn_mfma_f32_32x32x16_bf16(k##P##0, qf[0], SREG, 0, 0, 0); \
    SREG = __builtin_amdgcn_mfma_f32_32x32x16_bf16(k##P##1, qf[1], SREG, 0, 0, 0); \
    SREG = __builtin_amdgcn_mfma_f32_32x32x16_bf16(k##P##2, qf[2], SREG, 0, 0, 0); \
    SREG = __builtin_amdgcn_mfma_f32_32x32x16_bf16(k##P##3, qf[3], SREG, 0, 0, 0); \
    __builtin_amdgcn_s_setprio(0);                                            \
    if ((C) + 2 < 8) { LOADK(P, (C) + 2) }                                    \
  }

// finish chunk C (S in SREG, V set P), then prefetch V for C+2 into set P.
#define FIN_CHUNK(C, P, SREG)                                                 \
  {                                                                           \
    FINISH_CHUNK(SREG, v##P##0, v##P##1, v##P##2, v##P##3);                   \
    if ((C) + 2 < 8) { LOADV(P, (C) + 2) }                                    \
  }

// ---------------- Attention: swapped-operand flash with rel-pos bias ----------------
// grid 3072 = 96 bh * 32 q-blocks of 32 rows. 4 waves split k (256 keys each).
// K/V in frag-linear global layout -> coalesced b128 loads straight to VGPRs.
// 2-deep SOFTWARE PIPELINE: QK(c+1) (matrix pipe, independent sB) issued before
// FINISH(c) (VALU softmax on sA) -> the two pipes overlap within one wave.
// Extra cost: one in-flight S accumulator (+16 regs, stays in <=256 tier).
__global__ __launch_bounds__(256, 3)
void attn_kernel(const ushort* __restrict__ q, const ushort* __restrict__ k4,
                 const ushort* __restrict__ v4, const ushort* __restrict__ pe,
                 ushort* __restrict__ y) {
  __shared__ __align__(16) char smem[34816];
  ushort* Rl = (ushort*)smem;              // [32][258] bf16 (k-loop phase)
  float* OL  = (float*)smem;               // [4][64][33] f32 merge (aliases Rl)
  float* ML  = (float*)(smem + 33792);     // [4][2][32]

  const int tid = threadIdx.x;
  const int w = tid >> 6, lane = tid & 63;
  const int il = lane & 31;
  const int hb = lane >> 5;
  const int hi8 = hb * 8;
  const int half4 = hb * 4;

  // XCD-grouping swizzle
  const int bid = blockIdx.x;
  const int swz_b = (bid & 7) * 384 + (bid >> 3);
  const int bh = swz_b >> 5;
  const int q0 = (swz_b & 31) * 32;

  const ushort* qp = q + (size_t)bh * 65536;
  const ushort* kc = k4 + (size_t)bh * 65536 + w * 16384 + lane * 8;
  const ushort* vc = v4 + (size_t)bh * 65536 + w * 16384 + lane * 8;

  // Q fragments
  bf16x8 qf[4];
  #pragma unroll
  for (int ks = 0; ks < 4; ++ks)
    qf[ks] = *(const bf16x8*)(qp + (q0 + il) * 64 + ks * 16 + hi8);

  // issue chunk 0/1 K,V prefetch (lands during R phase)
  bf16x8 ka0, ka1, ka2, ka3, va0, va1, va2, va3;
  bf16x8 kb0, kb1, kb2, kb3, vb0, vb1, vb2, vb3;
  LOADK(a, 0) LOADV(a, 0)
  LOADK(b, 1) LOADV(b, 1)

  // R phase: R[i][p] = q_i . pe[p] (pre-scaled)
  #pragma unroll
  for (int pb = 0; pb < 2; ++pb) {
    const int pc0 = (w * 2 + pb) * 32;
    f32x16 r;
    #pragma unroll
    for (int i = 0; i < 16; ++i) r[i] = 0.f;
    #pragma unroll
    for (int ks = 0; ks < 4; ++ks) {
      bf16x8 pf = *(const bf16x8*)(pe + (pc0 + il) * 64 + ks * 16 + hi8);
      r = __builtin_amdgcn_mfma_f32_32x32x16_bf16(qf[ks], pf, r, 0, 0, 0);
    }
    #pragma unroll
    for (int i = 0; i < 16; ++i) {
      const int rr = (i & 3) + 8 * (i >> 2) + half4;
      Rl[rr * 258 + pc0 + il] = f2bf(r[i]);
    }
  }
  __syncthreads();

  const ushort* RlRow = Rl + il * 258;
  const float c_lo = bf2f(RlRow[128]);
  const float c_hi = bf2f(RlRow[127]);

  float m_run = -1e30f, l_run = 0.f;
  f32x16 o0, o1;
  #pragma unroll
  for (int i = 0; i < 16; ++i) { o0[i] = 0.f; o1[i] = 0.f; }

  // 2-deep pipeline: QK(c+1) before FIN(c); alternating S accumulators
  f32x16 sA, sB;
  QK_CHUNK(0, a, sA)
  QK_CHUNK(1, b, sB)  FIN_CHUNK(0, a, sA)
  QK_CHUNK(2, a, sA)  FIN_CHUNK(1, b, sB)
  QK_CHUNK(3, b, sB)  FIN_CHUNK(2, a, sA)
  QK_CHUNK(4, a, sA)  FIN_CHUNK(3, b, sB)
  QK_CHUNK(5, b, sB)  FIN_CHUNK(4, a, sA)
  QK_CHUNK(6, a, sA)  FIN_CHUNK(5, b, sB)
  QK_CHUNK(7, b, sB)  FIN_CHUNK(6, a, sA)
  FIN_CHUNK(7, b, sB)

  l_run += __shfl_xor(l_run, 32);   // complete the deferred cross-half l sum

  // ---- single-pass flash merge (OL holds all 64 output rows per wave) ----
  __syncthreads();   // all waves done reading Rl; safe to alias with OL
  #pragma unroll
  for (int i = 0; i < 16; ++i) {
    const int rr = (i & 3) + 8 * (i >> 2) + half4;
    OL[(w * 64 + rr) * 33 + il] = o0[i];
    OL[(w * 64 + 32 + rr) * 33 + il] = o1[i];
  }
  if (hb == 0) {
    ML[(w * 2) * 32 + il] = m_run;
    ML[(w * 2 + 1) * 32 + il] = l_run;
  }
  __syncthreads();

  const int mq = tid >> 3;           // q row 0..31
  const int dg = (tid & 7) * 8;      // d group 0,8,..,56
  float mw[4], lw[4];
  #pragma unroll
  for (int wv = 0; wv < 4; ++wv) {
    mw[wv] = ML[(wv * 2) * 32 + mq];
    lw[wv] = ML[(wv * 2 + 1) * 32 + mq];
  }
  const float ms = fmaxf(fmaxf(mw[0], mw[1]), fmaxf(mw[2], mw[3]));
  float cw[4], lst = 0.f;
  #pragma unroll
  for (int wv = 0; wv < 4; ++wv) {
    cw[wv] = __builtin_amdgcn_exp2f(mw[wv] - ms);
    lst += cw[wv] * lw[wv];
  }
  const float inv = 1.f / lst;

  float r8[8] = {0.f, 0.f, 0.f, 0.f, 0.f, 0.f, 0.f, 0.f};
  #pragma unroll
  for (int wv = 0; wv < 4; ++wv)
    #pragma unroll
    for (int e = 0; e < 8; ++e)
      r8[e] += cw[wv] * OL[(wv * 64 + dg + e) * 33 + mq];

  const int b = bh / NH, h = bh % NH;
  ushort* yrow = y + (size_t)(b * NS + q0 + mq) * NE + h * 64;
  union OU { bf16x8 v; ushort s[8]; } ou;
  #pragma unroll
  for (int e = 0; e < 8; ++e) ou.s[e] = f2bf(r8[e] * inv);
  *(bf16x8*)(yrow + dg) = ou.v;
}

// ---------------- launch ----------------
extern "C" void kernel_launch(void* const* d_in, const int* in_sizes, int n_in,
                              void* d_out, int out_size, void* d_ws, size_t ws_size,
                              hipStream_t stream) {
  const float* x  = (const float*)d_in[0];
  const float* Wq = (const float*)d_in[1];
  const float* Wk = (const float*)d_in[2];
  const float* Wv = (const float*)d_in[3];
  const float* Wp = (const float*)d_in[4];
  const float* pe = (const float*)d_in[5];

  ushort* ws  = (ushort*)d_ws;
  ushort* xb  = ws;                    // 6291456
  ushort* wqb = xb  + 6291456;         // 589824
  ushort* wkb = wqb + 589824;
  ushort* wvb = wkb + 589824;
  ushort* wpb = wvb + 589824;
  ushort* peb = wpb + 589824;          // 16384
  ushort* qb  = peb + 16384;           // 6291456
  ushort* k4b = qb  + 6291456;         // frag-linear K
  ushort* v4b = k4b + 6291456;         // frag-linear V
  ushort* yb  = v4b + 6291456;

  cvt_all<<<dim3(8464), dim3(256), 0, stream>>>(x, Wq, Wk, Wv, Wp, pe,
                                                xb, wqb, wkb, wvb, wpb, peb);
  gemm_qkv<<<dim3(64, 18), dim3(256), 0, stream>>>(xb, wqb, wkb, wvb, qb, k4b, v4b);
  attn_kernel<<<dim3(3072), dim3(256), 0, stream>>>(qb, k4b, v4b, peb, yb);
  gemm_proj<<<dim3(64, 6), dim3(256), 0, stream>>>(yb, wpb, (float*)d_out);
}

// Round 17
// 131.875 us; speedup vs baseline: 1.1783x; 1.1783x over previous
//
#include <hip/hip_runtime.h>

// Problem constants
#define NB 8
#define NS 1024
#define NE 768
#define NH 12
#define ND 64

typedef __attribute__((ext_vector_type(8))) short bf16x8;
typedef __attribute__((ext_vector_type(4))) float f32x4;
typedef __attribute__((ext_vector_type(16))) float f32x16;
typedef const __attribute__((address_space(1))) void gv_t;
typedef __attribute__((address_space(3))) void sv_t;

static __device__ __forceinline__ ushort f2bf(float f) {
  union { float f; unsigned u; } c; c.f = f;
  unsigned u = c.u + 0x7fffu + ((c.u >> 16) & 1u);
  return (ushort)(u >> 16);
}
static __device__ __forceinline__ float bf2f(ushort h) {
  union { unsigned u; float f; } c; c.u = ((unsigned)h) << 16;
  return c.f;
}
static __device__ __forceinline__ uint pk_bf16(float lo, float hi) {
  uint r;
  asm("v_cvt_pk_bf16_f32 %0, %1, %2" : "=v"(r) : "v"(lo), "v"(hi));
  return r;
}
// exchange lane halves (distinct, well-aged registers only)
#define PL32SWAP(a, b) asm("v_permlane32_swap_b32 %0, %1" : "+v"(a), "+v"(b))
#define GLDS16(src, dst) __builtin_amdgcn_global_load_lds((gv_t*)(src), (sv_t*)(dst), 16, 0, 0)

// ---------------- f32 -> bf16 conversion (x + all weights, one launch) ----------------
__global__ void cvt_all(const float* __restrict__ x,
                        const float* __restrict__ w0, const float* __restrict__ w1,
                        const float* __restrict__ w2, const float* __restrict__ w3,
                        const float* __restrict__ w4,
                        ushort* __restrict__ xd,
                        ushort* __restrict__ o0, ushort* __restrict__ o1,
                        ushort* __restrict__ o2, ushort* __restrict__ o3,
                        ushort* __restrict__ o4) {
  int blk = blockIdx.x;
  const float* src; ushort* dst; int idx;
  if (blk < 6144) {
    src = x; dst = xd; idx = blk;
  } else if (blk < 8448) {
    int b = blk - 6144;
    int ws = b / 576;
    src = (ws == 0) ? w0 : (ws == 1) ? w1 : (ws == 2) ? w2 : w3;
    dst = (ws == 0) ? o0 : (ws == 1) ? o1 : (ws == 2) ? o2 : o3;
    idx = b % 576;
  } else {
    src = w4; dst = o4; idx = blk - 8448;
  }
  int i = (idx * 256 + threadIdx.x) * 4;
  float4 f = *(const float4*)(src + i);
  ushort4 o;
  o.x = f2bf(f.x); o.y = f2bf(f.y); o.z = f2bf(f.z); o.w = f2bf(f.w);
  *(ushort4*)(dst + i) = o;
}

// ---------------- GEMM core: C[128x128] tile of A[M,768] @ B[N,768]^T ----------------
// 2-phase double-buffered with COUNTED vmcnt (T4): stage kt+1 issued at top of
// step kt and stays in flight across the whole compute phase; each wave waits
// only vmcnt(4) (its own stage(kt) loads) before barrier #1. lgkmcnt(0) +
// barrier #2 before MFMA licenses next step's overwrite of the read buffer.
// S0 layout (ushorts): As0@0, Bs0@4096, As1@8192, Bs1@12288.
__device__ __forceinline__ void gemm_core(const ushort* __restrict__ A,
                                          const ushort* __restrict__ Bw,
                                          ushort* S0,
                                          int bm0, int bn0, f32x4 (&acc)[4][4]) {
  const int tid = threadIdx.x;
  const int w = tid >> 6, lane = tid & 63;
  const int l15 = lane & 15, l4 = lane >> 4;
  const int wm = w >> 1, wn = w & 1;
  const int row = tid >> 2, seg = tid & 3;

#define STAGE_KT(KT, B)                                                        \
  { ushort* As_ = S0 + (B) * 8192; ushort* Bs_ = As_ + 4096;                   \
    _Pragma("unroll")                                                          \
    for (int p = 0; p < 2; ++p) {                                              \
      const ushort* ga = A + (size_t)(bm0 + p * 64 + row) * 768 + (KT) * 32 + seg * 8; \
      GLDS16(ga, As_ + (p * 256 + w * 64) * 8);                                \
      const ushort* gb = Bw + (size_t)(bn0 + p * 64 + row) * 768 + (KT) * 32 + seg * 8; \
      GLDS16(gb, Bs_ + (p * 256 + w * 64) * 8);                                \
    } }

  STAGE_KT(0, 0)   // 4 glds in flight

  #pragma unroll 2
  for (int kt = 0; kt < 24; ++kt) {
    if (kt < 23) { STAGE_KT(kt + 1, (kt + 1) & 1) }   // +4 -> 8 in flight

    // wait only for stage(kt); stage(kt+1) stays in flight across compute
    if (kt < 23) { asm volatile("s_waitcnt vmcnt(4)" ::: "memory"); }
    else         { asm volatile("s_waitcnt vmcnt(0)" ::: "memory"); }
    __builtin_amdgcn_sched_barrier(0);
    __builtin_amdgcn_s_barrier();      // #1: all waves' stage(kt) landed
    __builtin_amdgcn_sched_barrier(0);

    ushort* As = S0 + (kt & 1) * 8192;
    ushort* Bs = As + 4096;
    bf16x8 af[4], bf[4];
    #pragma unroll
    for (int mi = 0; mi < 4; ++mi)
      af[mi] = *(const bf16x8*)(As + (wm * 64 + mi * 16 + l15) * 32 + l4 * 8);
    #pragma unroll
    for (int ni = 0; ni < 4; ++ni)
      bf[ni] = *(const bf16x8*)(Bs + (wn * 64 + ni * 16 + l15) * 32 + l4 * 8);

    asm volatile("s_waitcnt lgkmcnt(0)" ::: "memory");
    __builtin_amdgcn_sched_barrier(0);
    __builtin_amdgcn_s_barrier();      // #2: all waves' ds_reads done ->
    __builtin_amdgcn_sched_barrier(0); //     next STAGE may overwrite this buf

    #pragma unroll
    for (int mi = 0; mi < 4; ++mi)
      #pragma unroll
      for (int ni = 0; ni < 4; ++ni)
        acc[mi][ni] = __builtin_amdgcn_mfma_f32_16x16x32_bf16(af[mi], bf[ni], acc[mi][ni], 0, 0, 0);
  }
#undef STAGE_KT
}

// QKV: blockIdx.y in [0,18): wsel = y/6 picks W/dst, bn = y%6
// q (PRE-SCALED by 1/sqrt(64)*log2e) written [bh][s][d].
// k written FRAG-LINEAR k4[bh][s>>5][d>>4][(d>>3)&1][s&31][d&7]
// v written FRAG-LINEAR v4[bh][s>>5][(d>>5)*2+((s>>4)&1)][(s>>3)&1][d&31][s&7]
__global__ __launch_bounds__(256)
void gemm_qkv(const ushort* __restrict__ A,
              const ushort* __restrict__ B0, const ushort* __restrict__ B1, const ushort* __restrict__ B2,
              ushort* __restrict__ C0, ushort* __restrict__ C1, ushort* __restrict__ C2) {
  __shared__ __align__(16) char gsm[34816];   // 32KB dbuf; VtS [128][136] aliases
  ushort* S0 = (ushort*)gsm;
  ushort* VtS = (ushort*)gsm;

  const int wsel = blockIdx.y / 6;
  const int bn0 = (blockIdx.y % 6) * 128;
  const int bx = blockIdx.x;
  const int bm0 = (((bx & 7) << 3) + (bx >> 3)) * 128;   // XCD-chunked swizzle
  const ushort* Bw = (wsel == 0) ? B0 : (wsel == 1) ? B1 : B2;
  ushort* Co = (wsel == 0) ? C0 : (wsel == 1) ? C1 : C2;

  f32x4 acc[4][4];
  #pragma unroll
  for (int i = 0; i < 4; ++i)
    #pragma unroll
    for (int j = 0; j < 4; ++j)
      acc[i][j] = (f32x4){0.f, 0.f, 0.f, 0.f};

  gemm_core(A, Bw, S0, bm0, bn0, acc);

  const int tid = threadIdx.x;
  const int lane = tid & 63;
  const int w = tid >> 6;
  const int l15 = lane & 15, l4 = lane >> 4;
  const int wm = w >> 1, wn = w & 1;

  if (wsel == 2) {
    // transpose through LDS, then bf16x8 stores in v4 frag-linear layout
    __syncthreads();
    #pragma unroll
    for (int mi = 0; mi < 4; ++mi) {
      #pragma unroll
      for (int ni = 0; ni < 4; ++ni) {
        const int nl = wn * 64 + ni * 16 + l15;
        const int ml = wm * 64 + mi * 16 + l4 * 4;
        ushort4 pk;
        pk.x = f2bf(acc[mi][ni][0]); pk.y = f2bf(acc[mi][ni][1]);
        pk.z = f2bf(acc[mi][ni][2]); pk.w = f2bf(acc[mi][ni][3]);
        *(ushort4*)&VtS[nl * 136 + ml] = pk;
      }
    }
    __syncthreads();
    #pragma unroll
    for (int p = 0; p < 8; ++p) {
      const int n = p * 16 + (tid >> 4);
      const int m = (tid & 15) * 8;
      bf16x8 vv = *(const bf16x8*)&VtS[n * 136 + m];
      const int ng = bn0 + n, h = ng >> 6, d = ng & 63;
      const int mg = bm0 + m, b = mg >> 10, sl = mg & 1023;
      size_t off = (size_t)(b * NH + h) * 65536 + (size_t)(sl >> 5) * 2048
                 + (size_t)((d >> 5) * 2 + ((sl >> 4) & 1)) * 512
                 + ((sl >> 3) & 1) * 256 + (d & 31) * 8;
      *(bf16x8*)&Co[off] = vv;
    }
  } else if (wsel == 1) {
    // k4 frag-linear scatter
    #pragma unroll
    for (int mi = 0; mi < 4; ++mi) {
      #pragma unroll
      for (int ni = 0; ni < 4; ++ni) {
        #pragma unroll
        for (int e = 0; e < 4; ++e) {
          int m = bm0 + wm * 64 + mi * 16 + l4 * 4 + e;
          int n = bn0 + wn * 64 + ni * 16 + l15;
          int b = m >> 10, s = m & 1023, h = n >> 6, d = n & 63;
          size_t off = (size_t)(b * NH + h) * 65536 + (size_t)(s >> 5) * 2048
                     + (size_t)(d >> 4) * 512 + ((d >> 3) & 1) * 256
                     + (s & 31) * 8 + (d & 7);
          Co[off] = f2bf(acc[mi][ni][e]);
        }
      }
    }
  } else {
    const float scl = 0.18033688f;  // q: 1/8 * log2(e)
    #pragma unroll
    for (int mi = 0; mi < 4; ++mi) {
      #pragma unroll
      for (int ni = 0; ni < 4; ++ni) {
        #pragma unroll
        for (int e = 0; e < 4; ++e) {
          int m = bm0 + wm * 64 + mi * 16 + l4 * 4 + e;
          int n = bn0 + wn * 64 + ni * 16 + l15;
          int b = m >> 10, s = m & 1023, h = n >> 6, d = n & 63;
          Co[(size_t)(b * NH + h) * 65536 + (s << 6) + d] = f2bf(acc[mi][ni][e] * scl);
        }
      }
    }
  }
}

// Output projection: y[8192,768] @ Wp^T -> f32 out
__global__ __launch_bounds__(256)
void gemm_proj(const ushort* __restrict__ A, const ushort* __restrict__ Bw,
               float* __restrict__ Cout) {
  __shared__ __align__(16) ushort S0[16384];   // 32KB double-buffer
  const int bx = blockIdx.x;
  const int bm0 = (((bx & 7) << 3) + (bx >> 3)) * 128;   // XCD-chunked swizzle
  const int bn0 = blockIdx.y * 128;

  f32x4 acc[4][4];
  #pragma unroll
  for (int i = 0; i < 4; ++i)
    #pragma unroll
    for (int j = 0; j < 4; ++j)
      acc[i][j] = (f32x4){0.f, 0.f, 0.f, 0.f};

  gemm_core(A, Bw, S0, bm0, bn0, acc);

  const int lane = threadIdx.x & 63;
  const int w = threadIdx.x >> 6;
  const int l15 = lane & 15, l4 = lane >> 4;
  const int wm = w >> 1, wn = w & 1;
  #pragma unroll
  for (int mi = 0; mi < 4; ++mi) {
    #pragma unroll
    for (int ni = 0; ni < 4; ++ni) {
      #pragma unroll
      for (int e = 0; e < 4; ++e) {
        int m = bm0 + wm * 64 + mi * 16 + l4 * 4 + e;
        int n = bn0 + wn * 64 + ni * 16 + l15;
        Cout[(size_t)m * NE + n] = acc[mi][ni][e];
      }
    }
  }
}

// finish chunk: online softmax + P-pack + PV (uses/updates m_run,l_run,o0,o1)
// cross-half shfl only on the rare rescale path (trigger uses 64-lane __any).
#define FINISH_CHUNK(S, VF00, VF01, VF10, VF11)                               \
  {                                                                           \
    float m01 = fmaxf(S[0], S[1]),  m23 = fmaxf(S[2], S[3]);                  \
    float m45 = fmaxf(S[4], S[5]),  m67 = fmaxf(S[6], S[7]);                  \
    float m89 = fmaxf(S[8], S[9]),  mab = fmaxf(S[10], S[11]);                \
    float mcd = fmaxf(S[12], S[13]), mef = fmaxf(S[14], S[15]);               \
    float cmax = fmaxf(fmaxf(fmaxf(m01, m23), fmaxf(m45, m67)),               \
                       fmaxf(fmaxf(m89, mab), fmaxf(mcd, mef)));              \
    if (__any(cmax > m_run + 8.f)) {      /* rare; wave-uniform */            \
      cmax = fmaxf(cmax, __shfl_xor(cmax, 32));                               \
      const float m_new = fmaxf(m_run, cmax);                                 \
      const float sc = __builtin_amdgcn_exp2f(m_run - m_new);                 \
      l_run *= sc;                                                            \
      m_run = m_new;                                                          \
      _Pragma("unroll")                                                       \
      for (int i = 0; i < 16; ++i) { o0[i] *= sc; o1[i] *= sc; }              \
    }                                                                         \
    _Pragma("unroll")                                                         \
    for (int i = 0; i < 16; ++i)                                              \
      S[i] = __builtin_amdgcn_exp2f(S[i] - m_run);                            \
    {                                                                         \
      float t0 = S[0] + S[1],   t1 = S[2] + S[3];                             \
      float t2 = S[4] + S[5],   t3 = S[6] + S[7];                             \
      float t4 = S[8] + S[9],   t5 = S[10] + S[11];                           \
      float t6 = S[12] + S[13], t7 = S[14] + S[15];                           \
      t0 += t1; t2 += t3; t4 += t5; t6 += t7;                                 \
      l_run += (t0 + t2) + (t4 + t6);                                         \
    }                                                                         \
    uint a0 = pk_bf16(S[0],  S[1]);                                           \
    uint a1 = pk_bf16(S[2],  S[3]);                                           \
    uint a2 = pk_bf16(S[4],  S[5]);                                           \
    uint a3 = pk_bf16(S[6],  S[7]);                                           \
    uint a4 = pk_bf16(S[8],  S[9]);                                           \
    uint a5 = pk_bf16(S[10], S[11]);                                          \
    uint a6 = pk_bf16(S[12], S[13]);                                          \
    uint a7 = pk_bf16(S[14], S[15]);                                          \
    PL32SWAP(a0, a2);                                                         \
    PL32SWAP(a1, a3);                                                         \
    PL32SWAP(a4, a6);                                                         \
    PL32SWAP(a5, a7);                                                         \
    union FU { bf16x8 v; uint u[4]; } f0, f1;                                 \
    f0.u[0] = a0; f0.u[1] = a1; f0.u[2] = a2; f0.u[3] = a3;                   \
    f1.u[0] = a4; f1.u[1] = a5; f1.u[2] = a6; f1.u[3] = a7;                   \
    __builtin_amdgcn_s_setprio(1);                                            \
    o0 = __builtin_amdgcn_mfma_f32_32x32x16_bf16(VF00, f0.v, o0, 0, 0, 0);    \
    o0 = __builtin_amdgcn_mfma_f32_32x32x16_bf16(VF01, f1.v, o0, 0, 0, 0);    \
    o1 = __builtin_amdgcn_mfma_f32_32x32x16_bf16(VF10, f0.v, o1, 0, 0, 0);    \
    o1 = __builtin_amdgcn_mfma_f32_32x32x16_bf16(VF11, f1.v, o1, 0, 0, 0);    \
    __builtin_amdgcn_s_setprio(0);                                            \
  }

// bias C-init for a chunk (reads only Rl)
static __device__ __forceinline__ f32x16 bias_init(int dlt, const ushort* RlRow,
                                                   float c_lo, float c_hi,
                                                   int half4, int il) {
  f32x16 s;
  if (dlt <= -160 || dlt >= 160) {
    const float cv = (dlt < 0) ? c_lo : c_hi;
    #pragma unroll
    for (int i = 0; i < 16; ++i) s[i] = cv;
  } else {
    #pragma unroll
    for (int i = 0; i < 16; ++i) {
      const int rr = (i & 3) + 8 * (i >> 2) + half4;
      int rel = dlt + rr - il;
      rel = rel < -128 ? -128 : (rel > 127 ? 127 : rel);
      s[i] = bf2f(RlRow[rel & 255]);
    }
  }
  return s;
}

// load a chunk's K / V fragments (coalesced b128, frag-linear global layout)
#define LOADK(P, C)                                                           \
  k##P##0 = *(const bf16x8*)(kc + (C) * 2048);                                \
  k##P##1 = *(const bf16x8*)(kc + (C) * 2048 + 512);                          \
  k##P##2 = *(const bf16x8*)(kc + (C) * 2048 + 1024);                         \
  k##P##3 = *(const bf16x8*)(kc + (C) * 2048 + 1536);
#define LOADV(P, C)                                                           \
  v##P##0 = *(const bf16x8*)(vc + (C) * 2048);                                \
  v##P##1 = *(const bf16x8*)(vc + (C) * 2048 + 512);                          \
  v##P##2 = *(const bf16x8*)(vc + (C) * 2048 + 1024);                         \
  v##P##3 = *(const bf16x8*)(vc + (C) * 2048 + 1536);

// one chunk: bias -> QK -> (prefetch K for C+2) -> finish -> (prefetch V for C+2)
#define CHUNK(C, P)                                                           \
  {                                                                           \
    f32x16 s = bias_init(w * 256 + (C) * 32 - q0, RlRow, c_lo, c_hi, half4, il); \
    __builtin_amdgcn_s_setprio(1);                                            \
    s = __builtin_amdgcn_mfma_f32_32x32x16_bf16(k##P##0, qf[0], s, 0, 0, 0);  \
    s = __builtin_amdgcn_mfma_f32_32x32x16_bf16(k##P##1, qf[1], s, 0, 0, 0);  \
    s = __builtin_amdgcn_mfma_f32_32x32x16_bf16(k##P##2, qf[2], s, 0, 0, 0);  \
    s = __builtin_amdgcn_mfma_f32_32x32x16_bf16(k##P##3, qf[3], s, 0, 0, 0);  \
    __builtin_amdgcn_s_setprio(0);                                            \
    if ((C) + 2 < 8) { LOADK(P, (C) + 2) }                                    \
    FINISH_CHUNK(s, v##P##0, v##P##1, v##P##2, v##P##3);                      \
    if ((C) + 2 < 8) { LOADV(P, (C) + 2) }                                    \
  }

// ---------------- Attention: swapped-operand flash with rel-pos bias ----------------
// grid 3072 = 96 bh * 32 q-blocks of 32 rows. 4 waves split k (256 keys each).
// K/V in frag-linear global layout -> coalesced b128 loads straight to VGPRs.
// bounds (256,3); K AND V ping-pong 2-ahead (round-11/15 proven register shape).
// NOTE: 2-deep S-pipeline (round 16) SPILLS (+16 live regs -> WRITE_SIZE 73MB);
// the live set at this occupancy is saturated -- keep serial CHUNK.
__global__ __launch_bounds__(256, 3)
void attn_kernel(const ushort* __restrict__ q, const ushort* __restrict__ k4,
                 const ushort* __restrict__ v4, const ushort* __restrict__ pe,
                 ushort* __restrict__ y) {
  __shared__ __align__(16) char smem[34816];
  ushort* Rl = (ushort*)smem;              // [32][258] bf16 (k-loop phase)
  float* OL  = (float*)smem;               // [4][64][33] f32 merge (aliases Rl)
  float* ML  = (float*)(smem + 33792);     // [4][2][32]

  const int tid = threadIdx.x;
  const int w = tid >> 6, lane = tid & 63;
  const int il = lane & 31;
  const int hb = lane >> 5;
  const int hi8 = hb * 8;
  const int half4 = hb * 4;

  // XCD-grouping swizzle
  const int bid = blockIdx.x;
  const int swz_b = (bid & 7) * 384 + (bid >> 3);
  const int bh = swz_b >> 5;
  const int q0 = (swz_b & 31) * 32;

  const ushort* qp = q + (size_t)bh * 65536;
  const ushort* kc = k4 + (size_t)bh * 65536 + w * 16384 + lane * 8;
  const ushort* vc = v4 + (size_t)bh * 65536 + w * 16384 + lane * 8;

  // Q fragments
  bf16x8 qf[4];
  #pragma unroll
  for (int ks = 0; ks < 4; ++ks)
    qf[ks] = *(const bf16x8*)(qp + (q0 + il) * 64 + ks * 16 + hi8);

  // issue chunk 0/1 K,V prefetch (lands during R phase)
  bf16x8 ka0, ka1, ka2, ka3, va0, va1, va2, va3;
  bf16x8 kb0, kb1, kb2, kb3, vb0, vb1, vb2, vb3;
  LOADK(a, 0) LOADV(a, 0)
  LOADK(b, 1) LOADV(b, 1)

  // R phase: R[i][p] = q_i . pe[p] (pre-scaled)
  #pragma unroll
  for (int pb = 0; pb < 2; ++pb) {
    const int pc0 = (w * 2 + pb) * 32;
    f32x16 r;
    #pragma unroll
    for (int i = 0; i < 16; ++i) r[i] = 0.f;
    #pragma unroll
    for (int ks = 0; ks < 4; ++ks) {
      bf16x8 pf = *(const bf16x8*)(pe + (pc0 + il) * 64 + ks * 16 + hi8);
      r = __builtin_amdgcn_mfma_f32_32x32x16_bf16(qf[ks], pf, r, 0, 0, 0);
    }
    #pragma unroll
    for (int i = 0; i < 16; ++i) {
      const int rr = (i & 3) + 8 * (i >> 2) + half4;
      Rl[rr * 258 + pc0 + il] = f2bf(r[i]);
    }
  }
  __syncthreads();

  const ushort* RlRow = Rl + il * 258;
  const float c_lo = bf2f(RlRow[128]);
  const float c_hi = bf2f(RlRow[127]);

  float m_run = -1e30f, l_run = 0.f;
  f32x16 o0, o1;
  #pragma unroll
  for (int i = 0; i < 16; ++i) { o0[i] = 0.f; o1[i] = 0.f; }

  // 8 chunks, fully unrolled, ping-pong sets
  CHUNK(0, a)
  CHUNK(1, b)
  CHUNK(2, a)
  CHUNK(3, b)
  CHUNK(4, a)
  CHUNK(5, b)
  CHUNK(6, a)
  CHUNK(7, b)

  l_run += __shfl_xor(l_run, 32);   // complete the deferred cross-half l sum

  // ---- single-pass flash merge (OL holds all 64 output rows per wave) ----
  __syncthreads();   // all waves done reading Rl; safe to alias with OL
  #pragma unroll
  for (int i = 0; i < 16; ++i) {
    const int rr = (i & 3) + 8 * (i >> 2) + half4;
    OL[(w * 64 + rr) * 33 + il] = o0[i];
    OL[(w * 64 + 32 + rr) * 33 + il] = o1[i];
  }
  if (hb == 0) {
    ML[(w * 2) * 32 + il] = m_run;
    ML[(w * 2 + 1) * 32 + il] = l_run;
  }
  __syncthreads();

  const int mq = tid >> 3;           // q row 0..31
  const int dg = (tid & 7) * 8;      // d group 0,8,..,56
  float mw[4], lw[4];
  #pragma unroll
  for (int wv = 0; wv < 4; ++wv) {
    mw[wv] = ML[(wv * 2) * 32 + mq];
    lw[wv] = ML[(wv * 2 + 1) * 32 + mq];
  }
  const float ms = fmaxf(fmaxf(mw[0], mw[1]), fmaxf(mw[2], mw[3]));
  float cw[4], lst = 0.f;
  #pragma unroll
  for (int wv = 0; wv < 4; ++wv) {
    cw[wv] = __builtin_amdgcn_exp2f(mw[wv] - ms);
    lst += cw[wv] * lw[wv];
  }
  const float inv = 1.f / lst;

  float r8[8] = {0.f, 0.f, 0.f, 0.f, 0.f, 0.f, 0.f, 0.f};
  #pragma unroll
  for (int wv = 0; wv < 4; ++wv)
    #pragma unroll
    for (int e = 0; e < 8; ++e)
      r8[e] += cw[wv] * OL[(wv * 64 + dg + e) * 33 + mq];

  const int b = bh / NH, h = bh % NH;
  ushort* yrow = y + (size_t)(b * NS + q0 + mq) * NE + h * 64;
  union OU { bf16x8 v; ushort s[8]; } ou;
  #pragma unroll
  for (int e = 0; e < 8; ++e) ou.s[e] = f2bf(r8[e] * inv);
  *(bf16x8*)(yrow + dg) = ou.v;
}

// ---------------- launch ----------------
extern "C" void kernel_launch(void* const* d_in, const int* in_sizes, int n_in,
                              void* d_out, int out_size, void* d_ws, size_t ws_size,
                              hipStream_t stream) {
  const float* x  = (const float*)d_in[0];
  const float* Wq = (const float*)d_in[1];
  const float* Wk = (const float*)d_in[2];
  const float* Wv = (const float*)d_in[3];
  const float* Wp = (const float*)d_in[4];
  const float* pe = (const float*)d_in[5];

  ushort* ws  = (ushort*)d_ws;
  ushort* xb  = ws;                    // 6291456
  ushort* wqb = xb  + 6291456;         // 589824
  ushort* wkb = wqb + 589824;
  ushort* wvb = wkb + 589824;
  ushort* wpb = wvb + 589824;
  ushort* peb = wpb + 589824;          // 16384
  ushort* qb  = peb + 16384;           // 6291456
  ushort* k4b = qb  + 6291456;         // frag-linear K
  ushort* v4b = k4b + 6291456;         // frag-linear V
  ushort* yb  = v4b + 6291456;

  cvt_all<<<dim3(8464), dim3(256), 0, stream>>>(x, Wq, Wk, Wv, Wp, pe,
                                                xb, wqb, wkb, wvb, wpb, peb);
  gemm_qkv<<<dim3(64, 18), dim3(256), 0, stream>>>(xb, wqb, wkb, wvb, qb, k4b, v4b);
  attn_kernel<<<dim3(3072), dim3(256), 0, stream>>>(qb, k4b, v4b, peb, yb);
  gemm_proj<<<dim3(64, 6), dim3(256), 0, stream>>>(yb, wpb, (float*)d_out);
}